// Round 6
// baseline (203.792 us; speedup 1.0000x reference)
//
#include <hip/hip_runtime.h>

// Correlation: out[b,(p+4)*9+(q+4),y,x] = (1/128) * sum_c A[b,c,y,x]*B[b,c,y+p,x+q]
// A,B = (8,128,128,128) fp32; out = (8,81,128,128) fp32. B zero-padded.
//
// R6: (y,p)-tiled blocks to cut cache-path traffic. Block = 384 thr (6 waves) =
// one (b, y-pair, p-group-of-3); wave = (y_l, p_l). B rows staged = 4 shared by
// 6 (y,p) cells; A rows = 2 shared by 3 p's -> 1.0 staged rows/(y*p) vs R5 1.33.
// Keeps f16 pair-packing + v_dot2_f32_f16 + LDS double-buffer (1 barrier/chunk)
// + 1-chunk-ahead register prefetch. LDS 17.4 KB/block -> 4-5 blocks/CU.

typedef __fp16 h2 __attribute__((ext_vector_type(2)));

#define BW2 144   // padded B row in h2 units; j = x+4, valid j in [0,136), pad 144

#if __has_builtin(__builtin_amdgcn_fdot2)
  #define FDOT2(a, b, c) __builtin_amdgcn_fdot2((a), (b), (c), false)
#else
  static __device__ inline float FDOT2(h2 a, h2 b, float c) {
      return c + (float)a.x * (float)b.x + (float)a.y * (float)b.y;
  }
#endif

static __device__ inline float pk2f(float lo, float hi) {
    h2 v = __builtin_amdgcn_cvt_pkrtz(lo, hi);   // (f16(lo), f16(hi)) packed
    return __builtin_bit_cast(float, v);
}
static __device__ inline h2 f2h2(float f) { return __builtin_bit_cast(h2, f); }

__global__ __launch_bounds__(384, 7)
void corr_kernel(const float* __restrict__ A, const float* __restrict__ B,
                 float* __restrict__ out)
{
    const int bidx = blockIdx.x;
    const int bb   = bidx & 7;        // batch -> XCD affinity
    const int rest = bidx >> 3;       // 0..191
    const int ygrp = rest & 63;
    const int pgrp = rest >> 6;       // 0..2
    const int y0   = ygrp << 1;

    const int tid  = threadIdx.x;     // 0..383
    const int wv   = tid >> 6;        // 0..5
    const int lane = tid & 63;
    const int cs   = lane >> 5;       // pair-select within 4-channel chunk
    const int x0   = (lane & 31) << 2;
    const int ylw  = wv & 1;          // wave's y_l (0/1)
    const int pl   = wv >> 1;         // wave's p_l (0..2)
    const int slot = ylw + pl;        // B row slot 0..3 (shared across waves)
    const int pr   = pgrp * 3 + pl;   // 0..8 -> p = pr-4

    __shared__ h2 a_s[2][2][2][128];  // [buf][y_l][pair][x]
    __shared__ h2 b_s[2][4][2][BW2];  // [buf][slot][pair][j]

    // one-time zero of b_s: pads (j<4, j>=132) and OOB rows stay zero forever
    {
        float4* pb = (float4*)&b_s[0][0][0][0];
        const int nb = 2 * 4 * 2 * BW2 / 4;   // 576 float4
        for (int i = tid; i < nb; i += 384) pb[i] = make_float4(0.f, 0.f, 0.f, 0.f);
    }

    float acc[9][4];
    #pragma unroll
    for (int q = 0; q < 9; ++q)
        #pragma unroll
        for (int i = 0; i < 4; ++i) acc[q][i] = 0.f;

    const long plane = 128L * 128L;
    const float* Abat = A + (long)bb * 128 * plane;
    const float* Bbat = B + (long)bb * 128 * plane;

    // ---- staging role: exactly one pack-unit per thread (256 B + 128 A)
    // unit = 2 global float4 loads (channels c, c+1) -> pack -> 1 LDS float4
    const bool brole = tid < 256;
    const float* gsrc;   // row base + column; add c*plane per chunk
    int gpair;           // pair within chunk (0/1)
    bool gvalid;
    h2* wptr0; h2* wptr1;
    if (brole) {
        const int col = tid & 31;
        gpair = (tid >> 5) & 1;
        const int sl = tid >> 6;                 // slot 0..3
        const int ys = y0 + pgrp * 3 - 4 + sl;   // B row = base + slot
        gvalid = (unsigned)ys < 128u;
        gsrc = Bbat + (long)ys * 128 + (col << 2);
        wptr0 = &b_s[0][sl][gpair][4 + (col << 2)];
        wptr1 = &b_s[1][sl][gpair][4 + (col << 2)];
    } else {
        const int u = tid - 256;
        const int col = u & 31;
        gpair = (u >> 5) & 1;
        const int yl = u >> 6;                   // 0..1
        gvalid = true;
        gsrc = Abat + (long)(y0 + yl) * 128 + (col << 2);
        wptr0 = &a_s[0][yl][gpair][col << 2];
        wptr1 = &a_s[1][yl][gpair][col << 2];
    }

    float4 r0 = make_float4(0.f, 0.f, 0.f, 0.f), r1 = r0;

    auto load_chunk = [&](int ch0) {
        if (gvalid) {
            const long off = (long)(ch0 + (gpair << 1)) * plane;
            r0 = *(const float4*)(gsrc + off);
            r1 = *(const float4*)(gsrc + off + plane);
        }
    };
    auto write_stage = [&](int buf) {
        if (gvalid) {
            float4 w;
            w.x = pk2f(r0.x, r1.x);
            w.y = pk2f(r0.y, r1.y);
            w.z = pk2f(r0.z, r1.z);
            w.w = pk2f(r0.w, r1.w);
            *(float4*)(buf ? wptr1 : wptr0) = w;
        }
    };

    // prologue: chunk0 -> buf0, start chunk1 loads
    load_chunk(0);
    __syncthreads();          // zero-init visible before first stage writes
    write_stage(0);
    load_chunk(4);
    __syncthreads();          // buf0 ready

    for (int k = 0; k < 32; ++k) {
        const int buf = k & 1;
        if (k + 1 < 32) write_stage(buf ^ 1);     // regs hold chunk k+1
        if (k + 2 < 32) load_chunk((k + 2) << 2); // overlap with compute
        // compute chunk k: wave's (y_l, p_l); lane's pair = cs
        {
            const float4 av = *(const float4*)&a_s[buf][ylw][cs][x0];
            const float4 b0 = *(const float4*)&b_s[buf][slot][cs][x0];
            const float4 b1 = *(const float4*)&b_s[buf][slot][cs][x0 + 4];
            const float4 b2 = *(const float4*)&b_s[buf][slot][cs][x0 + 8];
            const h2 a2[4] = { f2h2(av.x), f2h2(av.y), f2h2(av.z), f2h2(av.w) };
            const h2 w[12] = { f2h2(b0.x), f2h2(b0.y), f2h2(b0.z), f2h2(b0.w),
                               f2h2(b1.x), f2h2(b1.y), f2h2(b1.z), f2h2(b1.w),
                               f2h2(b2.x), f2h2(b2.y), f2h2(b2.z), f2h2(b2.w) };
            #pragma unroll
            for (int q = 0; q < 9; ++q)
                #pragma unroll
                for (int i = 0; i < 4; ++i)
                    acc[q][i] = FDOT2(a2[i], w[q + i], acc[q][i]);
        }
        __syncthreads();
    }

    // combine pair-split halves (lane L += lane L+32)
    #pragma unroll
    for (int q = 0; q < 9; ++q)
        #pragma unroll
        for (int i = 0; i < 4; ++i)
            acc[q][i] += __shfl_down(acc[q][i], 32);

    if (cs == 0) {
        const float scale = 1.0f / 128.0f;
        const int y = y0 + ylw;
        float* obase = out + (((long)bb * 81 + (long)pr * 9) * 128 + y) * 128 + x0;
        #pragma unroll
        for (int q = 0; q < 9; ++q) {
            const float4 v = make_float4(acc[q][0] * scale, acc[q][1] * scale,
                                         acc[q][2] * scale, acc[q][3] * scale);
            *(float4*)(obase + (long)q * plane) = v;
        }
    }
}

extern "C" void kernel_launch(void* const* d_in, const int* in_sizes, int n_in,
                              void* d_out, int out_size, void* d_ws, size_t ws_size,
                              hipStream_t stream) {
    const float* a = (const float*)d_in[0];
    const float* b = (const float*)d_in[1];
    float* out = (float*)d_out;
    // grid: 8 batches * 64 y-pairs * 3 p-groups = 1536 blocks; 384 threads (6 waves)
    hipLaunchKernelGGL(corr_kernel, dim3(1536), dim3(384), 0, stream, a, b, out);
}